// Round 1
// baseline (29972.592 us; speedup 1.0000x reference)
//
#include <hip/hip_runtime.h>

// LSTM forward: N=64, T=512, D=1024, H=1024
// out[n][t][h], fp32. Inputs: x(N,T,D) h0(N,H) Wx(D,4H) Wh(H,4H) b(4H), all fp32.

#define NB 64
#define TT 512
#define DD 1024
#define HH 1024
#define GG 4096

using f32x4  = __attribute__((ext_vector_type(4))) float;
using bf16x8 = __attribute__((ext_vector_type(8))) __bf16;
using u16x4  = __attribute__((ext_vector_type(4))) unsigned short;

__device__ inline unsigned short f2bf(float x) {
  union { float f; unsigned u; } v; v.f = x;
  unsigned r = v.u + 0x7fffu + ((v.u >> 16) & 1u);   // RNE
  return (unsigned short)(r >> 16);
}
__device__ inline float bfu2f(unsigned short u) {
  union { unsigned u; float f; } v; v.u = ((unsigned)u) << 16; return v.f;
}
__device__ inline float lof(unsigned u) { union { unsigned u; float f; } v; v.u = u << 16;          return v.f; }
__device__ inline float hif(unsigned u) { union { unsigned u; float f; } v; v.u = u & 0xffff0000u;  return v.f; }
__device__ inline float sigm(float x)     { return 1.0f / (1.0f + __expf(-x)); }
__device__ inline float tanhfast(float x) { return 1.0f - 2.0f / (__expf(2.0f * x) + 1.0f); }

// ---------------------------------------------------------------------------
// Transpose + cast: in fp32 [rows][cols]  ->  out bf16 [cols][rows]
// ---------------------------------------------------------------------------
__global__ __launch_bounds__(256) void tcast(const float* __restrict__ in,
                                             unsigned short* __restrict__ out,
                                             int rows, int cols) {
  __shared__ float tile[32][33];
  const int bx = blockIdx.x * 32;   // col base
  const int by = blockIdx.y * 32;   // row base
  const int tx = threadIdx.x;       // 0..31
  for (int i = threadIdx.y; i < 32; i += 8)
    tile[i][tx] = in[(size_t)(by + i) * cols + bx + tx];
  __syncthreads();
  for (int i = threadIdx.y; i < 32; i += 8)
    out[(size_t)(bx + i) * rows + by + tx] = f2bf(tile[tx][i]);
}

__global__ __launch_bounds__(1024) void zerok(float* __restrict__ p, int n) {
  int i = blockIdx.x * 1024 + threadIdx.x;
  if (i < n) p[i] = 0.0f;
}

// ---------------------------------------------------------------------------
// Phase 1: xw[m][g] = sum_k x[m][k] * Wx[k][g] + b[g]   (stored bf16)
// A = x fp32 [32768][1024] (cast to bf16 in staging), B = WxT bf16 [4096][1024]
// 128x128 tile, BK=64, 256 threads (4 waves, each 64x64), mfma_f32_16x16x32_bf16
// ---------------------------------------------------------------------------
#define BM 128
#define BN 128
#define BK 64
#define LDP (BK + 8)   // 72: row stride 144B (mult of 16, bank-spread)

__global__ __launch_bounds__(256) void gemm_xw(const float* __restrict__ x,
                                               const unsigned short* __restrict__ WxT,
                                               const float* __restrict__ bvec,
                                               unsigned short* __restrict__ xw) {
  __shared__ unsigned short As[BM][LDP];
  __shared__ unsigned short Bs[BN][LDP];
  const int tid  = threadIdx.x;
  const int m0   = blockIdx.y * BM;
  const int g0   = blockIdx.x * BN;
  const int wave = tid >> 6, lane = tid & 63;
  const int wm = (wave & 1) * 64, wn = (wave >> 1) * 64;
  const int lr = lane & 15, lk = (lane >> 4) * 8;

  f32x4 acc[4][4] = {};

  for (int kt = 0; kt < DD; kt += BK) {
    // stage A: 128 rows x 64 k of x, fp32 -> bf16
#pragma unroll
    for (int it = 0; it < 8; ++it) {
      const int row = it * 16 + (tid >> 4);
      const int c4  = (tid & 15) * 4;
      const float4 xv = *(const float4*)(x + (size_t)(m0 + row) * DD + kt + c4);
      u16x4 us; us.x = f2bf(xv.x); us.y = f2bf(xv.y); us.z = f2bf(xv.z); us.w = f2bf(xv.w);
      *(u16x4*)&As[row][c4] = us;
    }
    // stage B: 128 g-rows x 64 k of WxT (already bf16)
#pragma unroll
    for (int it = 0; it < 4; ++it) {
      const int row = it * 32 + (tid >> 3);
      const int c8  = (tid & 7) * 8;
      const uint4 wv = *(const uint4*)(WxT + (size_t)(g0 + row) * DD + kt + c8);
      *(uint4*)&Bs[row][c8] = wv;
    }
    __syncthreads();
#pragma unroll
    for (int ks = 0; ks < BK / 32; ++ks) {
      const int kk = ks * 32 + lk;
      bf16x8 af[4], bfv[4];
#pragma unroll
      for (int mi = 0; mi < 4; ++mi) af[mi]  = *(const bf16x8*)&As[wm + mi * 16 + lr][kk];
#pragma unroll
      for (int ni = 0; ni < 4; ++ni) bfv[ni] = *(const bf16x8*)&Bs[wn + ni * 16 + lr][kk];
#pragma unroll
      for (int mi = 0; mi < 4; ++mi)
#pragma unroll
        for (int ni = 0; ni < 4; ++ni)
          acc[mi][ni] = __builtin_amdgcn_mfma_f32_16x16x32_bf16(af[mi], bfv[ni], acc[mi][ni], 0, 0, 0);
    }
    __syncthreads();
  }

  // epilogue: D row=(lane>>4)*4+j, col=lane&15  [guide §3, m89-verified]
#pragma unroll
  for (int mi = 0; mi < 4; ++mi) {
    const int row = m0 + wm + mi * 16 + ((lane >> 4) << 2);
#pragma unroll
    for (int ni = 0; ni < 4; ++ni) {
      const int col = g0 + wn + ni * 16 + lr;
      const float bb = bvec[col];
#pragma unroll
      for (int j = 0; j < 4; ++j)
        xw[(size_t)(row + j) * GG + col] = f2bf(acc[mi][ni][j] + bb);
    }
  }
}

// ---------------------------------------------------------------------------
// Phase 2: one launch per timestep.
// a[r][g] = xw[r*T+t][g] + sum_k h_prev[r][k] * Wh[k][g]; gates; write h to out.
// 256 blocks x 256 threads; block owns 4 hidden cols; thread = (row r, col).
// h_prev read from out[t-1] (fp32), WhT bf16 rows are wave-uniform (scalar loads).
// ---------------------------------------------------------------------------
__global__ __launch_bounds__(256) void lstm_step(const float* __restrict__ hin, int hstride,
                                                 const unsigned short* __restrict__ WhT,
                                                 const unsigned short* __restrict__ xw,
                                                 float* __restrict__ cbuf,
                                                 float* __restrict__ out,
                                                 int t) {
  const int tid = threadIdx.x;
  const int r   = tid & 63;          // batch row
  const int cl  = tid >> 6;          // 0..3 (wave-uniform)
  const int col = blockIdx.x * 4 + cl;

  const float* hrow = hin + (size_t)r * hstride;
  const unsigned short* w0 = WhT + ((size_t)(0 * HH + col)) * HH;
  const unsigned short* w1 = WhT + ((size_t)(1 * HH + col)) * HH;
  const unsigned short* w2 = WhT + ((size_t)(2 * HH + col)) * HH;
  const unsigned short* w3 = WhT + ((size_t)(3 * HH + col)) * HH;

  float a0 = 0.f, a1 = 0.f, a2 = 0.f, a3 = 0.f;
#pragma unroll 2
  for (int k = 0; k < HH; k += 8) {
    const float4 ha = *(const float4*)(hrow + k);
    const float4 hb = *(const float4*)(hrow + k + 4);
    uint4 w;
#define DOT(ACC, WP)                                                           \
    w = *(const uint4*)(WP + k);                                               \
    ACC += ha.x * lof(w.x) + ha.y * hif(w.x) + ha.z * lof(w.y) + ha.w * hif(w.y) \
         + hb.x * lof(w.z) + hb.y * hif(w.z) + hb.z * lof(w.w) + hb.w * hif(w.w);
    DOT(a0, w0) DOT(a1, w1) DOT(a2, w2) DOT(a3, w3)
#undef DOT
  }

  const size_t mrow = (size_t)r * TT + t;
  const float ai = a0 + bfu2f(xw[mrow * GG + 0 * HH + col]);
  const float af = a1 + bfu2f(xw[mrow * GG + 1 * HH + col]);
  const float ao = a2 + bfu2f(xw[mrow * GG + 2 * HH + col]);
  const float ag = a3 + bfu2f(xw[mrow * GG + 3 * HH + col]);

  const float gi = sigm(ai), gf = sigm(af), go = sigm(ao), gg = tanhfast(ag);
  const size_t cidx = (size_t)r * HH + col;
  const float cn = gf * cbuf[cidx] + gi * gg;
  cbuf[cidx] = cn;
  out[mrow * HH + col] = go * tanhfast(cn);
}

// ---------------------------------------------------------------------------
extern "C" void kernel_launch(void* const* d_in, const int* in_sizes, int n_in,
                              void* d_out, int out_size, void* d_ws, size_t ws_size,
                              hipStream_t stream) {
  const float* x  = (const float*)d_in[0];
  const float* h0 = (const float*)d_in[1];
  const float* Wx = (const float*)d_in[2];
  const float* Wh = (const float*)d_in[3];
  const float* b  = (const float*)d_in[4];
  float* out = (float*)d_out;

  // workspace layout
  unsigned short* xw  = (unsigned short*)d_ws;              // 32768*4096 bf16 = 256 MB
  unsigned short* WxT = xw  + (size_t)NB * TT * GG;         // 4096*1024 bf16 = 8 MB
  unsigned short* WhT = WxT + (size_t)GG * DD;              // 8 MB
  float*          cb  = (float*)(WhT + (size_t)GG * HH);    // 64*1024 fp32 = 256 KB

  tcast<<<dim3(GG / 32, DD / 32), dim3(32, 8), 0, stream>>>(Wx, WxT, DD, GG);
  tcast<<<dim3(GG / 32, HH / 32), dim3(32, 8), 0, stream>>>(Wh, WhT, HH, GG);
  zerok<<<(NB * HH + 1023) / 1024, 1024, 0, stream>>>(cb, NB * HH);
  gemm_xw<<<dim3(GG / BN, NB * TT / BM), 256, 0, stream>>>(x, WxT, b, xw);

  for (int t = 0; t < TT; ++t) {
    const float* hin = (t == 0) ? h0 : (out + (size_t)(t - 1) * HH);
    const int hstride = (t == 0) ? HH : TT * HH;
    lstm_step<<<256, 256, 0, stream>>>(hin, hstride, WhT, xw, cb, out, t);
  }
}

// Round 2
// 17821.971 us; speedup vs baseline: 1.6818x; 1.6818x over previous
//
#include <hip/hip_runtime.h>

// LSTM forward: N=64, T=512, D=1024, H=1024
// out[n][t][h], fp32. Inputs: x(N,T,D) h0(N,H) Wx(D,4H) Wh(H,4H) b(4H), all fp32.

#define NB 64
#define TT 512
#define DD 1024
#define HH 1024
#define GG 4096

using f32x4  = __attribute__((ext_vector_type(4))) float;
using bf16x8 = __attribute__((ext_vector_type(8))) __bf16;
using u16x4  = __attribute__((ext_vector_type(4))) unsigned short;

__device__ inline unsigned short f2bf(float x) {
  union { float f; unsigned u; } v; v.f = x;
  unsigned r = v.u + 0x7fffu + ((v.u >> 16) & 1u);   // RNE
  return (unsigned short)(r >> 16);
}
__device__ inline float bfu2f(unsigned short u) {
  union { unsigned u; float f; } v; v.u = ((unsigned)u) << 16; return v.f;
}
__device__ inline float sigm(float x)     { return 1.0f / (1.0f + __expf(-x)); }
__device__ inline float tanhfast(float x) { return 1.0f - 2.0f / (__expf(2.0f * x) + 1.0f); }

// ---------------------------------------------------------------------------
// Transpose + cast: in fp32 [rows][cols]  ->  out bf16 [cols][rows]
// ---------------------------------------------------------------------------
__global__ __launch_bounds__(256) void tcast(const float* __restrict__ in,
                                             unsigned short* __restrict__ out,
                                             int rows, int cols) {
  __shared__ float tile[32][33];
  const int bx = blockIdx.x * 32;   // col base
  const int by = blockIdx.y * 32;   // row base
  const int tx = threadIdx.x;       // 0..31
  for (int i = threadIdx.y; i < 32; i += 8)
    tile[i][tx] = in[(size_t)(by + i) * cols + bx + tx];
  __syncthreads();
  for (int i = threadIdx.y; i < 32; i += 8)
    out[(size_t)(bx + i) * rows + by + tx] = f2bf(tile[tx][i]);
}

// init: h0 -> bf16 hi/lo planes (buffer 0), zero c
__global__ __launch_bounds__(256) void init_h(const float* __restrict__ h0,
                                              unsigned short* __restrict__ hhi,
                                              unsigned short* __restrict__ hlo,
                                              float* __restrict__ cb) {
  const int idx = blockIdx.x * 256 + threadIdx.x;   // 0 .. 65535
  const float v = h0[idx];
  const unsigned short hi = f2bf(v);
  hhi[idx] = hi;
  hlo[idx] = f2bf(v - bfu2f(hi));
  cb[idx] = 0.0f;
}

// ---------------------------------------------------------------------------
// Phase 1: xw[m][g] = sum_k x[m][k] * Wx[k][g] + b[g]   (stored bf16)
// 128x128 tile, BK=64, 256 threads (4 waves), mfma_f32_16x16x32_bf16
// ---------------------------------------------------------------------------
#define BM 128
#define BN 128
#define BK 64
#define LDP (BK + 8)

__global__ __launch_bounds__(256) void gemm_xw(const float* __restrict__ x,
                                               const unsigned short* __restrict__ WxT,
                                               const float* __restrict__ bvec,
                                               unsigned short* __restrict__ xw) {
  __shared__ unsigned short As[BM][LDP];
  __shared__ unsigned short Bs[BN][LDP];
  const int tid  = threadIdx.x;
  const int m0   = blockIdx.y * BM;
  const int g0   = blockIdx.x * BN;
  const int wave = tid >> 6, lane = tid & 63;
  const int wm = (wave & 1) * 64, wn = (wave >> 1) * 64;
  const int lr = lane & 15, lk = (lane >> 4) * 8;

  f32x4 acc[4][4] = {};

  for (int kt = 0; kt < DD; kt += BK) {
#pragma unroll
    for (int it = 0; it < 8; ++it) {
      const int row = it * 16 + (tid >> 4);
      const int c4  = (tid & 15) * 4;
      const float4 xv = *(const float4*)(x + (size_t)(m0 + row) * DD + kt + c4);
      u16x4 us; us.x = f2bf(xv.x); us.y = f2bf(xv.y); us.z = f2bf(xv.z); us.w = f2bf(xv.w);
      *(u16x4*)&As[row][c4] = us;
    }
#pragma unroll
    for (int it = 0; it < 4; ++it) {
      const int row = it * 32 + (tid >> 3);
      const int c8  = (tid & 7) * 8;
      const uint4 wv = *(const uint4*)(WxT + (size_t)(g0 + row) * DD + kt + c8);
      *(uint4*)&Bs[row][c8] = wv;
    }
    __syncthreads();
#pragma unroll
    for (int ks = 0; ks < BK / 32; ++ks) {
      const int kk = ks * 32 + lk;
      bf16x8 af[4], bfv[4];
#pragma unroll
      for (int mi = 0; mi < 4; ++mi) af[mi]  = *(const bf16x8*)&As[wm + mi * 16 + lr][kk];
#pragma unroll
      for (int ni = 0; ni < 4; ++ni) bfv[ni] = *(const bf16x8*)&Bs[wn + ni * 16 + lr][kk];
#pragma unroll
      for (int mi = 0; mi < 4; ++mi)
#pragma unroll
        for (int ni = 0; ni < 4; ++ni)
          acc[mi][ni] = __builtin_amdgcn_mfma_f32_16x16x32_bf16(af[mi], bfv[ni], acc[mi][ni], 0, 0, 0);
    }
    __syncthreads();
  }

#pragma unroll
  for (int mi = 0; mi < 4; ++mi) {
    const int row = m0 + wm + mi * 16 + ((lane >> 4) << 2);
#pragma unroll
    for (int ni = 0; ni < 4; ++ni) {
      const int col = g0 + wn + ni * 16 + lr;
      const float bb = bvec[col];
#pragma unroll
      for (int j = 0; j < 4; ++j)
        xw[(size_t)(row + j) * GG + col] = f2bf(acc[mi][ni][j] + bb);
    }
  }
}

// ---------------------------------------------------------------------------
// Phase 2: one launch per timestep, MFMA recurrent GEMM.
// 64 blocks x 256 threads (4 waves). Block owns 16 hidden cols (j0);
// wave w = gate w computes the 64x16 tile a[:, w*1024+j0 .. +16].
// h kept fp32-accurate via bf16 hi/lo split (2 MFMAs per B-frag).
// Register-prefetch pipeline: next K-tile's global loads issued before MFMA.
// ---------------------------------------------------------------------------
#define BK2 128
#define LDS2 (BK2 + 8)   // 136 u16 = 272B row stride (16B aligned, 2-way bank alias = free)

__global__ __launch_bounds__(256) void lstm_step(const unsigned short* __restrict__ WhT,
                                                 const unsigned short* __restrict__ xw,
                                                 const unsigned short* __restrict__ hhi,
                                                 const unsigned short* __restrict__ hlo,
                                                 unsigned short* __restrict__ nhhi,
                                                 unsigned short* __restrict__ nhlo,
                                                 float* __restrict__ cb,
                                                 float* __restrict__ out,
                                                 int t) {
  __shared__ __align__(16) unsigned char smem[3 * 64 * LDS2 * 2];
  unsigned short* As_hi = (unsigned short*)smem;            // [64][LDS2]
  unsigned short* As_lo = As_hi + 64 * LDS2;
  unsigned short* Bs    = As_lo + 64 * LDS2;
  float* abuf = (float*)smem;                               // [4][64][17], aliases As_hi

  const int tid  = threadIdx.x;
  const int j0   = blockIdx.x * 16;
  const int w    = tid >> 6;         // wave = gate
  const int lane = tid & 63;
  const int lr   = lane & 15;
  const int koff = (lane >> 4) * 8;

  f32x4 acc[4] = {};
  uint4 rAh[4], rAl[4], rB[4];

#define LOADREGS(KT)                                                          \
  {                                                                           \
    _Pragma("unroll")                                                         \
    for (int it = 0; it < 4; ++it) {                                          \
      const int u = it * 256 + tid;                                           \
      const int row = u >> 4;                                                 \
      const int c8 = (u & 15) * 8;                                            \
      const size_t hsrc = (size_t)row * HH + (KT) + c8;                       \
      rAh[it] = *(const uint4*)&hhi[hsrc];                                    \
      rAl[it] = *(const uint4*)&hlo[hsrc];                                    \
      const int gate = row >> 4, cc = row & 15;                               \
      rB[it] = *(const uint4*)&WhT[((size_t)(gate * HH + j0 + cc)) * HH + (KT) + c8]; \
    }                                                                         \
  }

  LOADREGS(0);

  for (int ki = 0; ki < DD / BK2; ++ki) {
    // commit staged registers to LDS
#pragma unroll
    for (int it = 0; it < 4; ++it) {
      const int u = it * 256 + tid;
      const int row = u >> 4;
      const int c8 = (u & 15) * 8;
      *(uint4*)&As_hi[row * LDS2 + c8] = rAh[it];
      *(uint4*)&As_lo[row * LDS2 + c8] = rAl[it];
      *(uint4*)&Bs[row * LDS2 + c8]    = rB[it];
    }
    __syncthreads();
    if (ki + 1 < DD / BK2) LOADREGS((ki + 1) * BK2);   // prefetch under MFMA

#pragma unroll
    for (int ks = 0; ks < BK2 / 32; ++ks) {
      const int kk = ks * 32 + koff;
      const bf16x8 bv = *(const bf16x8*)&Bs[(w * 16 + lr) * LDS2 + kk];
#pragma unroll
      for (int mi = 0; mi < 4; ++mi) {
        const bf16x8 ah = *(const bf16x8*)&As_hi[(mi * 16 + lr) * LDS2 + kk];
        const bf16x8 al = *(const bf16x8*)&As_lo[(mi * 16 + lr) * LDS2 + kk];
        acc[mi] = __builtin_amdgcn_mfma_f32_16x16x32_bf16(ah, bv, acc[mi], 0, 0, 0);
        acc[mi] = __builtin_amdgcn_mfma_f32_16x16x32_bf16(al, bv, acc[mi], 0, 0, 0);
      }
    }
    __syncthreads();
  }
#undef LOADREGS

  // gate-tile -> LDS (aliases staging buffers; safe after final barrier)
#pragma unroll
  for (int mi = 0; mi < 4; ++mi) {
    const int row = mi * 16 + ((lane >> 4) << 2);
#pragma unroll
    for (int j = 0; j < 4; ++j)
      abuf[(w * 64 + row + j) * 17 + lr] = acc[mi][j];
  }
  __syncthreads();

  // gates + state update: 1024 elements, 4 per thread
#pragma unroll
  for (int k2 = 0; k2 < 4; ++k2) {
    const int idx = k2 * 256 + tid;
    const int row = idx >> 4;
    const int col = idx & 15;
    const size_t xrow = ((size_t)row * TT + t) * GG + j0 + col;
    const float ai = abuf[(0 * 64 + row) * 17 + col] + bfu2f(xw[xrow]);
    const float af = abuf[(1 * 64 + row) * 17 + col] + bfu2f(xw[xrow + HH]);
    const float ao = abuf[(2 * 64 + row) * 17 + col] + bfu2f(xw[xrow + 2 * HH]);
    const float ag = abuf[(3 * 64 + row) * 17 + col] + bfu2f(xw[xrow + 3 * HH]);

    const float gi = sigm(ai), gf = sigm(af), go = sigm(ao), gg = tanhfast(ag);
    const size_t cidx = (size_t)row * HH + j0 + col;
    const float cn = gf * cb[cidx] + gi * gg;
    cb[cidx] = cn;
    const float hn = go * tanhfast(cn);
    out[((size_t)row * TT + t) * HH + j0 + col] = hn;
    const unsigned short hi = f2bf(hn);
    nhhi[cidx] = hi;
    nhlo[cidx] = f2bf(hn - bfu2f(hi));
  }
}

// ---------------------------------------------------------------------------
extern "C" void kernel_launch(void* const* d_in, const int* in_sizes, int n_in,
                              void* d_out, int out_size, void* d_ws, size_t ws_size,
                              hipStream_t stream) {
  const float* x  = (const float*)d_in[0];
  const float* h0 = (const float*)d_in[1];
  const float* Wx = (const float*)d_in[2];
  const float* Wh = (const float*)d_in[3];
  const float* b  = (const float*)d_in[4];
  float* out = (float*)d_out;

  // workspace layout
  unsigned short* xw  = (unsigned short*)d_ws;              // 32768*4096 bf16 = 256 MB
  unsigned short* WxT = xw  + (size_t)NB * TT * GG;         // 8 MB
  unsigned short* WhT = WxT + (size_t)GG * DD;              // 8 MB
  float*          cb  = (float*)(WhT + (size_t)GG * HH);    // 256 KB
  unsigned short* hbuf = (unsigned short*)(cb + (size_t)NB * HH); // 2 bufs x (hi+lo) x 64K

  const size_t NH = (size_t)NB * HH;
  unsigned short* hhi[2] = { hbuf,            hbuf + 2 * NH };
  unsigned short* hlo[2] = { hbuf + NH,       hbuf + 3 * NH };

  tcast<<<dim3(GG / 32, DD / 32), dim3(32, 8), 0, stream>>>(Wx, WxT, DD, GG);
  tcast<<<dim3(GG / 32, HH / 32), dim3(32, 8), 0, stream>>>(Wh, WhT, HH, GG);
  init_h<<<NB * HH / 256, 256, 0, stream>>>(h0, hhi[0], hlo[0], cb);
  gemm_xw<<<dim3(GG / BN, NB * TT / BM), 256, 0, stream>>>(x, WxT, b, xw);

  for (int t = 0; t < TT; ++t) {
    const int ri = t & 1, wi = (t + 1) & 1;
    lstm_step<<<64, 256, 0, stream>>>(WhT, xw, hhi[ri], hlo[ri],
                                      hhi[wi], hlo[wi], cb, out, t);
  }
}